// Round 11
// baseline (126.191 us; speedup 1.0000x reference)
//
#include <hip/hip_runtime.h>
#include <hip/hip_bf16.h>
#include <math.h>

#define BN 32
#define NN 2048
#define KK 32
#define DD 16
#define SC 32        // split copies of s (atomic chain = 256/32 = 8)
#define ACC_C 4      // split copies of moment accumulators
#define ACC_STRIDE 33792  // per-copy: N[1024] + Sx[16384] + Sxx[16384]
#define PRM_STRIDE 36     // per (b,k): mu[16], ik[16], ck, pad[3]

// ws layout (floats):
// 0        : accA   [135168]
// 135168   : accB   [135168]
// 270336   : s      [SC*16384 = 524288]   (zero block: 0..794624)
// 794624   : prm    [1024*36 = 36864]
// 831488   : R      [BN*NN*KK = 2097152]  ([b][n][k], fully rewritten per iter)
// 2928640  : xpk    [524288]              (x bf16 A-fragments, 1M ushorts)

typedef __attribute__((ext_vector_type(8))) short bf16x8;
typedef __attribute__((ext_vector_type(16))) float f32x16;

static __device__ __forceinline__ ushort f2bf(float f) {
    unsigned int u = __float_as_uint(f);
    return (ushort)((u + 0x7FFFu + ((u >> 16) & 1u)) >> 16);  // RNE
}
static __device__ __forceinline__ short f2bfs(float f) {
    __hip_bfloat16 h = __float2bfloat16(f);  // HW RNE cvt
    return *reinterpret_cast<short*>(&h);
}

__global__ void k_zero(float4* __restrict__ p) {
    int i = blockIdx.x * 256 + threadIdx.x;
    p[i] = make_float4(0.f, 0.f, 0.f, 0.f);
}

// gamma: thread-per-n. All 32 logits in registers -> in-register softmax,
// zero shuffles. Params are block-uniform -> scalar s_loads.
// Writes R[b][n][0..31] = 128B contiguous per thread (8 float4 stores).
template <int FIRST>
__global__ __launch_bounds__(256) void k_gamma(
    const float* __restrict__ x, const float* __restrict__ mu0,
    const float* __restrict__ prm, float* __restrict__ R) {
    const int b = blockIdx.x >> 3;
    const int n = (blockIdx.x & 7) * 256 + threadIdx.x;

    float xv[DD];
    {
        const float4* xp = (const float4*)(x + ((size_t)b * NN + n) * DD);
#pragma unroll
        for (int q = 0; q < 4; q++) {
            float4 v = xp[q];
            xv[q*4+0]=v.x; xv[q*4+1]=v.y; xv[q*4+2]=v.z; xv[q*4+3]=v.w;
        }
    }

    float l[KK];
    float m = -3.0e38f;
#pragma unroll
    for (int k = 0; k < KK; k++) {
        float qd = 0.f, ck;
        if (FIRST) {
            const float4* mp = (const float4*)(mu0 + (size_t)(b * KK + k) * DD);
#pragma unroll
            for (int q = 0; q < 4; q++) {
                float4 m4 = mp[q];
                float z0 = xv[q*4+0] - m4.x, z1 = xv[q*4+1] - m4.y;
                float z2 = xv[q*4+2] - m4.z, z3 = xv[q*4+3] - m4.w;
                qd = fmaf(z0, z0, qd); qd = fmaf(z1, z1, qd);
                qd = fmaf(z2, z2, qd); qd = fmaf(z3, z3, qd);
            }
            ck = -3.4657359028f;  // log(1/32)
        } else {
            const float* pp = prm + (size_t)(b * KK + k) * PRM_STRIDE;
            const float4* mp = (const float4*)pp;
            const float4* ip = (const float4*)(pp + 16);
#pragma unroll
            for (int q = 0; q < 4; q++) {
                float4 m4 = mp[q], i4 = ip[q];
                float z0 = (xv[q*4+0] - m4.x) * i4.x;
                float z1 = (xv[q*4+1] - m4.y) * i4.y;
                float z2 = (xv[q*4+2] - m4.z) * i4.z;
                float z3 = (xv[q*4+3] - m4.w) * i4.w;
                qd = fmaf(z0, z0, qd); qd = fmaf(z1, z1, qd);
                qd = fmaf(z2, z2, qd); qd = fmaf(z3, z3, qd);
            }
            ck = pp[32];
        }
        l[k] = ck - 0.5f * qd;
        m = fmaxf(m, l[k]);
    }
    float ssum = 0.f;
#pragma unroll
    for (int k = 0; k < KK; k++) {
        float e = __expf(l[k] - m);
        ssum += e;
        l[k] = e;
    }
    const float inv = 1.0f / ssum;
    float4* Rr = (float4*)(R + ((size_t)b * NN + n) * KK);
#pragma unroll
    for (int q = 0; q < 8; q++) {
        float4 v = make_float4(l[q*4+0]*inv, l[q*4+1]*inv, l[q*4+2]*inv, l[q*4+3]*inv);
        Rr[q] = v;
    }
}

// moments: lane = k, 2 n per wave-iter; reads R (coalesced dword) + x
// (uniform row broadcast). No softmax work. Split-copy atomics.
__global__ __launch_bounds__(256, 4) void k_moments(
    const float* __restrict__ x, const float* __restrict__ R,
    float* __restrict__ accOut) {
    const int b = blockIdx.x >> 4;      // 32 b
    const int chunk = blockIdx.x & 15;  // 16 chunks of 128 n
    const int tid = threadIdx.x;
    const int wave = tid >> 6;
    const int lane = tid & 63;
    const int k = lane & 31;
    const int jj = lane >> 5;

    float aN = 0.f, aSx[DD], aSxx[DD];
#pragma unroll
    for (int d = 0; d < DD; d++) { aSx[d] = 0.f; aSxx[d] = 0.f; }

#pragma unroll 4
    for (int i = 0; i < 16; i++) {
        const int n = chunk * 128 + i * 8 + wave * 2 + jj;
        const float4* xp = (const float4*)(x + ((size_t)b * NN + n) * DD);
        float xv[DD];
#pragma unroll
        for (int q = 0; q < 4; q++) {
            float4 v = xp[q];
            xv[q*4+0]=v.x; xv[q*4+1]=v.y; xv[q*4+2]=v.z; xv[q*4+3]=v.w;
        }
        float g = R[((size_t)b * NN + n) * KK + k];
        aN += g;
#pragma unroll
        for (int d = 0; d < DD; d++) {
            aSx[d] = fmaf(g, xv[d], aSx[d]);
            aSxx[d] = fmaf(g * xv[d], xv[d], aSxx[d]);
        }
    }

    __shared__ float red[4][KK * 33];
    aN += __shfl_xor(aN, 32);
#pragma unroll
    for (int d = 0; d < DD; d++) {
        aSx[d] += __shfl_xor(aSx[d], 32);
        aSxx[d] += __shfl_xor(aSxx[d], 32);
    }
    if (jj == 0) {
        red[wave][k * 33 + 0] = aN;
#pragma unroll
        for (int d = 0; d < DD; d++) {
            red[wave][k * 33 + 1 + d] = aSx[d];
            red[wave][k * 33 + 17 + d] = aSxx[d];
        }
    }
    __syncthreads();
    float* outc = accOut + (size_t)(chunk & (ACC_C - 1)) * ACC_STRIDE;
    for (int idx = tid; idx < KK * 33; idx += 256) {
        float v = red[0][idx] + red[1][idx] + red[2][idx] + red[3][idx];
        int kk2 = idx / 33, j = idx % 33;
        float* dst;
        if (j == 0) dst = outc + b * KK + kk2;
        else if (j < 17) dst = outc + 1024 + (size_t)(b * KK + kk2) * DD + (j - 1);
        else dst = outc + 17408 + (size_t)(b * KK + kk2) * DD + (j - 17);
        unsafeAtomicAdd(dst, v);
    }
}

// finalize moments -> params (mu, 1/sigma, ck = log pi - sum log sigma)
__global__ void k_param(const float* __restrict__ accIn, float* __restrict__ prm) {
    int i = blockIdx.x * 256 + threadIdx.x;  // (b,k)
    if (i >= BN * KK) return;
    float N = 0.f, sxv[DD], sxxv[DD];
#pragma unroll
    for (int d = 0; d < DD; d++) { sxv[d] = 0.f; sxxv[d] = 0.f; }
#pragma unroll
    for (int c = 0; c < ACC_C; c++) {
        const float* base = accIn + (size_t)c * ACC_STRIDE;
        N += base[i];
        const float4* sxp  = (const float4*)(base + 1024  + (size_t)i * DD);
        const float4* sxxp = (const float4*)(base + 17408 + (size_t)i * DD);
#pragma unroll
        for (int q = 0; q < 4; q++) {
            float4 a = sxp[q], c2 = sxxp[q];
            sxv[q*4+0]+=a.x; sxv[q*4+1]+=a.y; sxv[q*4+2]+=a.z; sxv[q*4+3]+=a.w;
            sxxv[q*4+0]+=c2.x; sxxv[q*4+1]+=c2.y; sxxv[q*4+2]+=c2.z; sxxv[q*4+3]+=c2.w;
        }
    }
    float invN = 1.0f / N;
    float sumlog = 0.f;
    float* pp = prm + (size_t)i * PRM_STRIDE;
#pragma unroll
    for (int d = 0; d < DD; d++) {
        float m_ = sxv[d] * invN;
        float v = fmaxf(sxxv[d] * invN - m_ * m_, 1e-12f);
        pp[d] = m_;
        pp[16 + d] = rsqrtf(v);
        sumlog += __logf(v);
    }
    pp[32] = __logf(N * (1.0f / NN)) - 0.5f * sumlog;
}

// pack x into bf16 A-fragments: xpk[n][lane][8], lane l -> (b=l&31, e=8*(l>>5)..)
__global__ __launch_bounds__(256) void k_xpack(const float* __restrict__ x,
                                               ushort* __restrict__ xpk) {
    int idx = blockIdx.x * 256 + threadIdx.x;   // n*64 + l
    int n = idx >> 6, l = idx & 63;
    int b = l & 31, e0 = (l >> 5) * 8;
    const float4* xp = (const float4*)(x + ((size_t)b * NN + n) * DD + e0);
    float4 a = xp[0], c = xp[1];
    ushort* o = xpk + (size_t)idx * 8;
    o[0]=f2bf(a.x); o[1]=f2bf(a.y); o[2]=f2bf(a.z); o[3]=f2bf(a.w);
    o[4]=f2bf(c.x); o[5]=f2bf(c.y); o[6]=f2bf(c.z); o[7]=f2bf(c.w);
}

// MFMA caps: per (wave, n): D[32b x 32kd] = mfma_32x32x16_bf16(x-frag, W-frag),
// then sacc[q] += r(q) * D[q].  W cvt via HW __float2bfloat16.
__global__ __launch_bounds__(256, 4) void k_caps(
    const float* __restrict__ W, const ushort* __restrict__ xpk,
    const float* __restrict__ R, float* __restrict__ s) {
    const int tid = threadIdx.x;
    const int wv = tid >> 6, l = tid & 63;
    const int chunk = blockIdx.x >> 2, tg = blockIdx.x & 3;
    const int t = tg * 4 + wv;          // kd-tile 0..15
    const int col = l & 31, hi = l >> 5;
    const int kq = (l >> 4) & 1;        // k = 2t + kq
    float* sc = s + (size_t)(chunk & (SC - 1)) * (BN * KK * DD);

    float sacc[16];
#pragma unroll
    for (int q = 0; q < 16; q++) sacc[q] = 0.f;
    const f32x16 zacc = {0.f,0.f,0.f,0.f, 0.f,0.f,0.f,0.f,
                         0.f,0.f,0.f,0.f, 0.f,0.f,0.f,0.f};

#pragma unroll 4
    for (int i = 0; i < 8; i++) {
        const int n = chunk * 8 + i;
        bf16x8 af = *(const bf16x8*)(xpk + ((size_t)n * 64 + l) * 8);
        const float4* wp = (const float4*)(W + (((size_t)n * 512 + t * 32 + col) * DD) + hi * 8);
        float4 wlo = wp[0], whi = wp[1];
        bf16x8 bfr;
        bfr[0]=f2bfs(wlo.x); bfr[1]=f2bfs(wlo.y);
        bfr[2]=f2bfs(wlo.z); bfr[3]=f2bfs(wlo.w);
        bfr[4]=f2bfs(whi.x); bfr[5]=f2bfs(whi.y);
        bfr[6]=f2bfs(whi.z); bfr[7]=f2bfs(whi.w);
        const float* rn = R + (size_t)(4 * hi) * (NN * KK) + (size_t)n * KK + 2 * t + kq;
        float r0  = rn[(size_t) 0 * (NN * KK)];
        float r1  = rn[(size_t) 1 * (NN * KK)];
        float r2  = rn[(size_t) 2 * (NN * KK)];
        float r3  = rn[(size_t) 3 * (NN * KK)];
        float r4  = rn[(size_t) 8 * (NN * KK)];
        float r5  = rn[(size_t) 9 * (NN * KK)];
        float r6  = rn[(size_t)10 * (NN * KK)];
        float r7  = rn[(size_t)11 * (NN * KK)];
        float r8  = rn[(size_t)16 * (NN * KK)];
        float r9  = rn[(size_t)17 * (NN * KK)];
        float r10 = rn[(size_t)18 * (NN * KK)];
        float r11 = rn[(size_t)19 * (NN * KK)];
        float r12 = rn[(size_t)24 * (NN * KK)];
        float r13 = rn[(size_t)25 * (NN * KK)];
        float r14 = rn[(size_t)26 * (NN * KK)];
        float r15 = rn[(size_t)27 * (NN * KK)];

        f32x16 D = __builtin_amdgcn_mfma_f32_32x32x16_bf16(af, bfr, zacc, 0, 0, 0);

        sacc[0]  = fmaf(r0,  D[0],  sacc[0]);
        sacc[1]  = fmaf(r1,  D[1],  sacc[1]);
        sacc[2]  = fmaf(r2,  D[2],  sacc[2]);
        sacc[3]  = fmaf(r3,  D[3],  sacc[3]);
        sacc[4]  = fmaf(r4,  D[4],  sacc[4]);
        sacc[5]  = fmaf(r5,  D[5],  sacc[5]);
        sacc[6]  = fmaf(r6,  D[6],  sacc[6]);
        sacc[7]  = fmaf(r7,  D[7],  sacc[7]);
        sacc[8]  = fmaf(r8,  D[8],  sacc[8]);
        sacc[9]  = fmaf(r9,  D[9],  sacc[9]);
        sacc[10] = fmaf(r10, D[10], sacc[10]);
        sacc[11] = fmaf(r11, D[11], sacc[11]);
        sacc[12] = fmaf(r12, D[12], sacc[12]);
        sacc[13] = fmaf(r13, D[13], sacc[13]);
        sacc[14] = fmaf(r14, D[14], sacc[14]);
        sacc[15] = fmaf(r15, D[15], sacc[15]);
    }

    const int kd = t * 32 + col;
#pragma unroll
    for (int q = 0; q < 16; q++) {
        const int b = (q & 3) + 8 * (q >> 2) + 4 * hi;  // verified C/D row map
        unsafeAtomicAdd(sc + (size_t)b * (KK * DD) + kd, sacc[q]);
    }
}

__global__ void k_squash(const float* __restrict__ s, float* __restrict__ out) {
    int idx = blockIdx.x * 256 + threadIdx.x;  // 16384 = BN*KK*DD
    float v = 0.f;
#pragma unroll 8
    for (int c = 0; c < SC; c++) v += s[(size_t)c * (BN * KK * DD) + idx];
    float ss = v * v;
#pragma unroll
    for (int off = 1; off < 16; off <<= 1) ss += __shfl_xor(ss, off);
    ss += 1e-7f;
    float scale = sqrtf(ss) / (1.0f + ss);
    out[idx] = v * scale;
}

extern "C" void kernel_launch(void* const* d_in, const int* in_sizes, int n_in,
                              void* d_out, int out_size, void* d_ws, size_t ws_size,
                              hipStream_t stream) {
    const float* x   = (const float*)d_in[0];
    const float* W   = (const float*)d_in[1];
    const float* mu0 = (const float*)d_in[2];
    float* ws   = (float*)d_ws;
    float* accA = ws;
    float* accB = ws + 135168;
    float* s    = ws + 270336;
    float* prm  = ws + 794624;
    float* R    = ws + 831488;
    ushort* xpk = (ushort*)(ws + 2928640);

    k_zero<<<776, 256, 0, stream>>>((float4*)ws);   // accA+accB+s
    k_xpack<<<512, 256, 0, stream>>>(x, xpk);

    // EM iteration 1 (params = mu0, sigma=1, pi=1/32)
    k_gamma<1><<<256, 256, 0, stream>>>(x, mu0, nullptr, R);
    k_moments<<<512, 256, 0, stream>>>(x, R, accA);
    k_param<<<4, 256, 0, stream>>>(accA, prm);
    // EM iteration 2
    k_gamma<0><<<256, 256, 0, stream>>>(x, nullptr, prm, R);
    k_moments<<<512, 256, 0, stream>>>(x, R, accB);
    k_param<<<4, 256, 0, stream>>>(accB, prm);
    // EM iteration 3: gamma only (R final)
    k_gamma<0><<<256, 256, 0, stream>>>(x, nullptr, prm, R);

    k_caps<<<1024, 256, 0, stream>>>(W, xpk, R, s);
    k_squash<<<64, 256, 0, stream>>>(s, (float*)d_out);
}

// Round 12
// 100.425 us; speedup vs baseline: 1.2566x; 1.2566x over previous
//
#include <hip/hip_runtime.h>
#include <hip/hip_bf16.h>
#include <math.h>

#define BN 32
#define NN 2048
#define KK 32
#define DD 16
#define PART_C 16          // per-b partial copies (= n-chunks per b)
#define PART_STRIDE 1056   // per (b,c): [33][32] = (1+16+16) x 32
#define SCAPS 256          // s copies: one per caps chunk -> plain stores

// ws layout (floats):
// 0        : partialA [32*16*1056 = 540672]
// 540672   : partialB [540672]
// 1081344  : s        [256*16384 = 4194304]
// 5275648  : R        [BN*NN*KK = 2097152]
// 7372800  : xpk      [1048576 ushorts = 524288 floats]
// total ~7.9M floats ~= 31.6 MB

typedef __attribute__((ext_vector_type(8))) short bf16x8;
typedef __attribute__((ext_vector_type(16))) float f32x16;

static __device__ __forceinline__ ushort f2bf(float f) {
    unsigned int u = __float_as_uint(f);
    return (ushort)((u + 0x7FFFu + ((u >> 16) & 1u)) >> 16);  // RNE
}

// ---------- estep body (device fn) ----------
// MODE 0: write per-chunk moment partials (no atomics). MODE 1: write R.
// FIRST 1: params from mu0 (sigma=1, pi=1/32); else inline-finalize from partIn.
template <int MODE, int FIRST>
static __device__ __forceinline__ void estep_body(
    int blk, const float* __restrict__ x, const float* __restrict__ mu0,
    const float* __restrict__ partIn, float* __restrict__ partOut,
    float* __restrict__ Rout) {
    const int b = blk >> 4;       // 32 b
    const int chunk = blk & 15;   // 16 chunks of 128 n
    const int tid = threadIdx.x;
    const int wave = tid >> 6;
    const int lane = tid & 63;
    const int k = lane & 31;
    const int jj = lane >> 5;

    float mk[DD], ik[DD], ck;
    if (FIRST) {
        const float4* mp = (const float4*)(mu0 + (size_t)(b * KK + k) * DD);
#pragma unroll
        for (int q = 0; q < 4; q++) {
            float4 m4 = mp[q];
            mk[q*4+0]=m4.x; mk[q*4+1]=m4.y; mk[q*4+2]=m4.z; mk[q*4+3]=m4.w;
        }
#pragma unroll
        for (int d = 0; d < DD; d++) ik[d] = 1.0f;
        ck = -3.4657359028f;  // log(1/32)
    } else {
        // sum 16 per-chunk partials for this (b,k): coalesced dword loads
        float N = 0.f, sxv[DD], sxxv[DD];
#pragma unroll
        for (int d = 0; d < DD; d++) { sxv[d] = 0.f; sxxv[d] = 0.f; }
#pragma unroll
        for (int c = 0; c < PART_C; c++) {
            const float* base = partIn + (size_t)(b * PART_C + c) * PART_STRIDE;
            N += base[k];
#pragma unroll
            for (int d = 0; d < DD; d++) {
                sxv[d]  += base[(1 + d) * 32 + k];
                sxxv[d] += base[(17 + d) * 32 + k];
            }
        }
        float invN = 1.0f / N;
        float sumlog = 0.f;
#pragma unroll
        for (int d = 0; d < DD; d++) {
            float m_ = sxv[d] * invN;
            float v = fmaxf(sxxv[d] * invN - m_ * m_, 1e-12f);
            mk[d] = m_;
            ik[d] = rsqrtf(v);
            sumlog += __logf(v);
        }
        ck = __logf(N * (1.0f / NN)) - 0.5f * sumlog;
    }

    float aN = 0.f, aSx[DD], aSxx[DD];
#pragma unroll
    for (int d = 0; d < DD; d++) { aSx[d] = 0.f; aSxx[d] = 0.f; }

#pragma unroll 4
    for (int i = 0; i < 16; i++) {
        const int n = chunk * 128 + i * 8 + wave * 2 + jj;
        const float4* xp = (const float4*)(x + ((size_t)b * NN + n) * DD);
        float xv[DD];
#pragma unroll
        for (int q = 0; q < 4; q++) {
            float4 v = xp[q];
            xv[q*4+0]=v.x; xv[q*4+1]=v.y; xv[q*4+2]=v.z; xv[q*4+3]=v.w;
        }
        float qd = 0.f;
#pragma unroll
        for (int d = 0; d < DD; d++) {
            float z = (xv[d] - mk[d]) * ik[d];
            qd = fmaf(z, z, qd);
        }
        float logit = ck - 0.5f * qd;
        float m = logit;
#pragma unroll
        for (int off = 1; off < 32; off <<= 1) m = fmaxf(m, __shfl_xor(m, off));
        float e = __expf(logit - m);
        float ssum = e;
#pragma unroll
        for (int off = 1; off < 32; off <<= 1) ssum += __shfl_xor(ssum, off);
        float g = e / ssum;

        if (MODE == 1) {
            Rout[((size_t)b * NN + n) * KK + k] = g;  // coalesced per half-wave
        } else {
            aN += g;
#pragma unroll
            for (int d = 0; d < DD; d++) {
                aSx[d] = fmaf(g, xv[d], aSx[d]);
                aSxx[d] = fmaf(g * xv[d], xv[d], aSxx[d]);
            }
        }
    }

    if (MODE == 0) {
        __shared__ float red[4][KK * 33];
        aN += __shfl_xor(aN, 32);
#pragma unroll
        for (int d = 0; d < DD; d++) {
            aSx[d] += __shfl_xor(aSx[d], 32);
            aSxx[d] += __shfl_xor(aSxx[d], 32);
        }
        if (jj == 0) {
            red[wave][k * 33 + 0] = aN;
#pragma unroll
            for (int d = 0; d < DD; d++) {
                red[wave][k * 33 + 1 + d] = aSx[d];
                red[wave][k * 33 + 17 + d] = aSxx[d];
            }
        }
        __syncthreads();
        // plain coalesced stores of this chunk's partial [j][k]
        float* outp = partOut + (size_t)(b * PART_C + chunk) * PART_STRIDE;
        for (int idx = tid; idx < KK * 33; idx += 256) {
            int kk = idx & 31, j = idx >> 5;
            float v = red[0][kk * 33 + j] + red[1][kk * 33 + j] +
                      red[2][kk * 33 + j] + red[3][kk * 33 + j];
            outp[idx] = v;
        }
    }
}

static __device__ __forceinline__ void xpack_body(int blk, const float* __restrict__ x,
                                                  ushort* __restrict__ xpk) {
    int idx = blk * 256 + threadIdx.x;   // n*64 + l, total 131072
    int n = idx >> 6, l = idx & 63;
    int b = l & 31, e0 = (l >> 5) * 8;
    const float4* xp = (const float4*)(x + ((size_t)b * NN + n) * DD + e0);
    float4 a = xp[0], c = xp[1];
    ushort* o = xpk + (size_t)idx * 8;
    o[0]=f2bf(a.x); o[1]=f2bf(a.y); o[2]=f2bf(a.z); o[3]=f2bf(a.w);
    o[4]=f2bf(c.x); o[5]=f2bf(c.y); o[6]=f2bf(c.z); o[7]=f2bf(c.w);
}

// dispatch 1: blocks [0,512) = estep iter1; blocks [512,1024) = xpack
__global__ __launch_bounds__(256, 4) void k_fused1(
    const float* __restrict__ x, const float* __restrict__ mu0,
    float* __restrict__ partOut, ushort* __restrict__ xpk) {
    if (blockIdx.x < 512)
        estep_body<0, 1>(blockIdx.x, x, mu0, nullptr, partOut, nullptr);
    else
        xpack_body(blockIdx.x - 512, x, xpk);
}

template <int MODE>
__global__ __launch_bounds__(256, 4) void k_estep(
    const float* __restrict__ x, const float* __restrict__ partIn,
    float* __restrict__ partOut, float* __restrict__ Rout) {
    estep_body<MODE, 0>(blockIdx.x, x, nullptr, partIn, partOut, Rout);
}

// MFMA caps: per (wave, n): D[32b x 32kd] = mfma_32x32x16_bf16(x-frag, W-frag),
// then sacc[q] += r(q)*D[q]. One s copy per chunk -> plain stores, no zeroing.
__global__ __launch_bounds__(256, 4) void k_caps(
    const float* __restrict__ W, const ushort* __restrict__ xpk,
    const float* __restrict__ R, float* __restrict__ s) {
    const int tid = threadIdx.x;
    const int wv = tid >> 6, l = tid & 63;
    const int chunk = blockIdx.x >> 2, tg = blockIdx.x & 3;
    const int t = tg * 4 + wv;          // kd-tile 0..15
    const int col = l & 31, hi = l >> 5;
    const int kq = (l >> 4) & 1;        // k = 2t + kq
    float* sc = s + (size_t)chunk * (BN * KK * DD);

    float sacc[16];
#pragma unroll
    for (int q = 0; q < 16; q++) sacc[q] = 0.f;
    const f32x16 zacc = {0.f,0.f,0.f,0.f, 0.f,0.f,0.f,0.f,
                         0.f,0.f,0.f,0.f, 0.f,0.f,0.f,0.f};

#pragma unroll 4
    for (int i = 0; i < 8; i++) {
        const int n = chunk * 8 + i;
        bf16x8 af = *(const bf16x8*)(xpk + ((size_t)n * 64 + l) * 8);
        const float4* wp = (const float4*)(W + (((size_t)n * 512 + t * 32 + col) * DD) + hi * 8);
        float4 wlo = wp[0], whi = wp[1];
        bf16x8 bfr;
        bfr[0]=(short)f2bf(wlo.x); bfr[1]=(short)f2bf(wlo.y);
        bfr[2]=(short)f2bf(wlo.z); bfr[3]=(short)f2bf(wlo.w);
        bfr[4]=(short)f2bf(whi.x); bfr[5]=(short)f2bf(whi.y);
        bfr[6]=(short)f2bf(whi.z); bfr[7]=(short)f2bf(whi.w);
        const float* rn = R + (size_t)(4 * hi) * (NN * KK) + (size_t)n * KK + 2 * t + kq;
        float r0  = rn[(size_t) 0 * (NN * KK)];
        float r1  = rn[(size_t) 1 * (NN * KK)];
        float r2  = rn[(size_t) 2 * (NN * KK)];
        float r3  = rn[(size_t) 3 * (NN * KK)];
        float r4  = rn[(size_t) 8 * (NN * KK)];
        float r5  = rn[(size_t) 9 * (NN * KK)];
        float r6  = rn[(size_t)10 * (NN * KK)];
        float r7  = rn[(size_t)11 * (NN * KK)];
        float r8  = rn[(size_t)16 * (NN * KK)];
        float r9  = rn[(size_t)17 * (NN * KK)];
        float r10 = rn[(size_t)18 * (NN * KK)];
        float r11 = rn[(size_t)19 * (NN * KK)];
        float r12 = rn[(size_t)24 * (NN * KK)];
        float r13 = rn[(size_t)25 * (NN * KK)];
        float r14 = rn[(size_t)26 * (NN * KK)];
        float r15 = rn[(size_t)27 * (NN * KK)];

        f32x16 D = __builtin_amdgcn_mfma_f32_32x32x16_bf16(af, bfr, zacc, 0, 0, 0);

        sacc[0]  = fmaf(r0,  D[0],  sacc[0]);
        sacc[1]  = fmaf(r1,  D[1],  sacc[1]);
        sacc[2]  = fmaf(r2,  D[2],  sacc[2]);
        sacc[3]  = fmaf(r3,  D[3],  sacc[3]);
        sacc[4]  = fmaf(r4,  D[4],  sacc[4]);
        sacc[5]  = fmaf(r5,  D[5],  sacc[5]);
        sacc[6]  = fmaf(r6,  D[6],  sacc[6]);
        sacc[7]  = fmaf(r7,  D[7],  sacc[7]);
        sacc[8]  = fmaf(r8,  D[8],  sacc[8]);
        sacc[9]  = fmaf(r9,  D[9],  sacc[9]);
        sacc[10] = fmaf(r10, D[10], sacc[10]);
        sacc[11] = fmaf(r11, D[11], sacc[11]);
        sacc[12] = fmaf(r12, D[12], sacc[12]);
        sacc[13] = fmaf(r13, D[13], sacc[13]);
        sacc[14] = fmaf(r14, D[14], sacc[14]);
        sacc[15] = fmaf(r15, D[15], sacc[15]);
    }

    const int kd = t * 32 + col;
#pragma unroll
    for (int q = 0; q < 16; q++) {
        const int b = (q & 3) + 8 * (q >> 2) + 4 * hi;  // verified C/D row map
        sc[(size_t)b * (KK * DD) + kd] = sacc[q];       // plain store (disjoint)
    }
}

// thread per (b,k,d); sum SCAPS copies; 16-lane shuffle for the norm.
__global__ void k_squash(const float* __restrict__ s, float* __restrict__ out) {
    int idx = blockIdx.x * 256 + threadIdx.x;  // 16384 = BN*KK*DD
    float v = 0.f;
#pragma unroll 8
    for (int c = 0; c < SCAPS; c++) v += s[(size_t)c * (BN * KK * DD) + idx];
    float ss = v * v;
#pragma unroll
    for (int off = 1; off < 16; off <<= 1) ss += __shfl_xor(ss, off);
    ss += 1e-7f;
    float scale = sqrtf(ss) / (1.0f + ss);
    out[idx] = v * scale;
}

extern "C" void kernel_launch(void* const* d_in, const int* in_sizes, int n_in,
                              void* d_out, int out_size, void* d_ws, size_t ws_size,
                              hipStream_t stream) {
    const float* x   = (const float*)d_in[0];
    const float* W   = (const float*)d_in[1];
    const float* mu0 = (const float*)d_in[2];
    float* ws    = (float*)d_ws;
    float* partA = ws;
    float* partB = ws + 540672;
    float* s     = ws + 1081344;
    float* R     = ws + 5275648;
    ushort* xpk  = (ushort*)(ws + 7372800);

    // 1: EM iter1 partials + x bf16 pack (independent, fused)
    k_fused1<<<1024, 256, 0, stream>>>(x, mu0, partA, xpk);
    // 2: EM iter2 (inline-finalize from partA) -> partB
    k_estep<0><<<512, 256, 0, stream>>>(x, partA, partB, nullptr);
    // 3: EM iter3 (inline-finalize from partB) -> R
    k_estep<1><<<512, 256, 0, stream>>>(x, partB, nullptr, R);
    // 4: caps einsum (MFMA), plain stores into per-chunk s copies
    k_caps<<<1024, 256, 0, stream>>>(W, xpk, R, s);
    // 5: reduce copies + squash
    k_squash<<<64, 256, 0, stream>>>(s, (float*)d_out);
}